// Round 11
// baseline (59.321 us; speedup 1.0000x reference)
//
#include <hip/hip_runtime.h>
#include <math.h>

// Problem constants: N=2048, L=8, D=64, M=N=2048.
#define N_B 2048
#define L_L 8
#define D_D 64

typedef short bf16x8 __attribute__((ext_vector_type(8)));
typedef float f32x4 __attribute__((ext_vector_type(4)));
typedef unsigned short ushort8v __attribute__((ext_vector_type(8)));

#if __has_builtin(__builtin_amdgcn_exp2f)
#define EXP2(x) __builtin_amdgcn_exp2f(x)
#else
#define EXP2(x) exp2f(x)
#endif

// ---- device-coherent (cross-XCD) access helpers: sc0 sc1 bypass L1/L2 ----
__device__ __forceinline__ void store_f32_sys(float* p, float v) {
  asm volatile("global_store_dword %0, %1, off sc0 sc1" ::"v"(p), "v"(v)
               : "memory");
}
__device__ __forceinline__ unsigned load_u32_sys(const unsigned* p) {
  unsigned v;
  asm volatile("global_load_dword %0, %1, off sc0 sc1\n\ts_waitcnt vmcnt(0)"
               : "=v"(v) : "v"(p) : "memory");
  return v;
}
__device__ __forceinline__ f32x4 load_f32x4_sys_nowait(const float* p) {
  f32x4 v;
  asm volatile("global_load_dwordx4 %0, %1, off sc0 sc1"
               : "=v"(v) : "v"(p) : "memory");
  return v;
}
#define VM_WAIT0 asm volatile("s_waitcnt vmcnt(0)" ::: "memory")

// Split fp32 x into bf16 hi + bf16 lo (RTNE each). hi in high16, lo in low16.
__device__ __forceinline__ unsigned split_bf16_pack(float x) {
  unsigned u = __float_as_uint(x);
  unsigned rb = u + 0x7FFFu + ((u >> 16) & 1u);
  unsigned hbits = rb & 0xFFFF0000u;
  float res = x - __uint_as_float(hbits);
  unsigned u2 = __float_as_uint(res);
  unsigned rb2 = u2 + 0x7FFFu + ((u2 >> 16) & 1u);
  return hbits | (rb2 >> 16);
}

// Split 8 contiguous floats (scaled) into hi/lo ushort8 vectors.
__device__ __forceinline__ void split8(const float* __restrict__ src,
                                       float scale, ushort8v& H, ushort8v& L,
                                       float* ssq) {
  float4 v0 = *(const float4*)(src);
  float4 v1 = *(const float4*)(src + 4);
  float vv[8] = {v0.x, v0.y, v0.z, v0.w, v1.x, v1.y, v1.z, v1.w};
  #pragma unroll
  for (int t = 0; t < 8; ++t) {
    if (ssq) *ssq += vv[t] * vv[t];
    unsigned p = split_bf16_pack(scale * vv[t]);
    H[t] = (unsigned short)(p >> 16);
    L[t] = (unsigned short)(p & 0xFFFF);
  }
}

// Load 16 floats (k0..k0+7, k0+32..k0+39) from a 64-float row, split to frags.
// Works for LDS rows too (generic pointer -> ds_read after inlining).
__device__ __forceinline__ void load_split_row(const float* base, int k0,
                                               bf16x8& H0, bf16x8& L0,
                                               bf16x8& H1, bf16x8& L1) {
  float4 a0 = *(const float4*)(base + k0);
  float4 a1 = *(const float4*)(base + k0 + 4);
  float4 b0 = *(const float4*)(base + k0 + 32);
  float4 b1 = *(const float4*)(base + k0 + 36);
  float vv[16] = {a0.x, a0.y, a0.z, a0.w, a1.x, a1.y, a1.z, a1.w,
                  b0.x, b0.y, b0.z, b0.w, b1.x, b1.y, b1.z, b1.w};
  #pragma unroll
  for (int t = 0; t < 8; ++t) {
    unsigned p0 = split_bf16_pack(vv[t]);
    H0[t] = (short)(p0 >> 16); L0[t] = (short)(p0 & 0xFFFF);
    unsigned p1 = split_bf16_pack(vv[8 + t]);
    H1[t] = (short)(p1 >> 16); L1[t] = (short)(p1 & 0xFFFF);
  }
}

// ---------------------------------------------------------------------------
// K1: independent prep work in one launch.
//  bid [0,512):   e-split, XCD-aligned: l = bid&7 so esh rows for latent l are
//                 written on XCD l (lse consumer for l also runs on XCD l).
//  bid [512,768): encode: LDS-stage z-tile + encW-tile (coalesced), split from
//                 LDS, 6 split-MFMAs -> zm, zh/zl, ez = exp2(ap*||h||^2)
//  bid [768,784): decW split -> dwh/dwl
// ---------------------------------------------------------------------------
__global__ __launch_bounds__(256) void k1_prep_encode(
    const float* __restrict__ z, const float* __restrict__ e,
    const float* __restrict__ encW, const float* __restrict__ encb,
    const float* __restrict__ decW, const float* __restrict__ lsg,
    float* __restrict__ zm,
    unsigned short* __restrict__ esh, unsigned short* __restrict__ esl,
    float* __restrict__ en2G,
    unsigned short* __restrict__ zhG, unsigned short* __restrict__ zlG,
    float* __restrict__ ezG,
    unsigned short* __restrict__ dwh, unsigned short* __restrict__ dwl) {
  __shared__ __align__(16) float zT[64][68];  // 68-pad: 272B rows, 16B-aligned
  __shared__ __align__(16) float wT[64][68];
  const unsigned bid = blockIdx.x;
  const int tid = threadIdx.x;
  const int lane = tid & 63;
  const int wave = tid >> 6;
  const int bm = lane & 15;
  const int kg = lane >> 4;
  const int k0 = kg << 3;

  const float ls = lsg[0];
  const float sig = __expf(ls);
  const float ap = (-1.0f / (2.0f * sig * sig)) * 1.4426950408889634f;
  const float se = -2.0f * ap;

  if (bid < 512) {
    // e-split: block handles 32 rows of latent l = bid&7
    const int l = bid & 7;
    const int sub = bid >> 3;                  // 0..63
    const int row = l * N_B + (sub << 5) + (tid >> 3);
    const int c = (tid & 7) << 3;
    size_t off = (size_t)row * 64 + c;
    ushort8v H, L;
    float ssq = 0.f;
    split8(e + off, se, H, L, &ssq);
    *(ushort8v*)(esh + off) = H;
    *(ushort8v*)(esl + off) = L;
    ssq += __shfl_xor(ssq, 1);
    ssq += __shfl_xor(ssq, 2);
    ssq += __shfl_xor(ssq, 4);
    if ((tid & 7) == 0) en2G[row] = ssq;
  } else if (bid < 768) {
    const int eb = bid - 512;
    const int l = eb & 7;                      // XCD l gets latent l
    const int nt = eb >> 3;
    const int n0 = nt << 6;
    // ---- coalesced global -> LDS staging of z-tile and encW-tile ----
    {
      int r = tid >> 2, q = (tid & 3) << 4;
      const float4* zsrc = (const float4*)(z + (size_t)(n0 + r) * 64 + q);
      const float4* wsrc = (const float4*)(encW + (size_t)(l * 64 + r) * 64 + q);
      #pragma unroll
      for (int j = 0; j < 4; ++j) {
        *(float4*)&zT[r][q + j * 4] = zsrc[j];
        *(float4*)&wT[r][q + j * 4] = wsrc[j];
      }
    }
    __syncthreads();
    bf16x8 Bh0[4], Bh1[4], Bl0[4], Bl1[4];
    #pragma unroll
    for (int ms = 0; ms < 4; ++ms)
      load_split_row(&wT[ms * 16 + bm][0], k0,
                     Bh0[ms], Bl0[ms], Bh1[ms], Bl1[ms]);
    bf16x8 ah0, al0, ah1, al1;
    load_split_row(&zT[(wave << 4) + bm][0], k0, ah0, al0, ah1, al1);

    float sq[4] = {0.f, 0.f, 0.f, 0.f};
    #pragma unroll
    for (int ms = 0; ms < 4; ++ms) {
      float bi = encb[l * 64 + ms * 16 + bm];
      f32x4 acc = {bi, bi, bi, bi};
      acc = __builtin_amdgcn_mfma_f32_16x16x32_bf16(ah0, Bh0[ms], acc, 0, 0, 0);
      acc = __builtin_amdgcn_mfma_f32_16x16x32_bf16(ah1, Bh1[ms], acc, 0, 0, 0);
      acc = __builtin_amdgcn_mfma_f32_16x16x32_bf16(al0, Bh0[ms], acc, 0, 0, 0);
      acc = __builtin_amdgcn_mfma_f32_16x16x32_bf16(al1, Bh1[ms], acc, 0, 0, 0);
      acc = __builtin_amdgcn_mfma_f32_16x16x32_bf16(ah0, Bl0[ms], acc, 0, 0, 0);
      acc = __builtin_amdgcn_mfma_f32_16x16x32_bf16(ah1, Bl1[ms], acc, 0, 0, 0);
      #pragma unroll
      for (int r = 0; r < 4; ++r) {
        float v = acc[r];
        int nr = n0 + (wave << 4) + (kg << 2) + r;
        size_t idx = ((size_t)(l * N_B + nr)) * 64 + (ms << 4) + bm;
        zm[idx] = v;
        unsigned p = split_bf16_pack(v);
        zhG[idx] = (unsigned short)(p >> 16);
        zlG[idx] = (unsigned short)(p & 0xFFFF);
        sq[r] += v * v;
      }
    }
    #pragma unroll
    for (int r = 0; r < 4; ++r) {
      float s = sq[r];
      s += __shfl_xor(s, 1);
      s += __shfl_xor(s, 2);
      s += __shfl_xor(s, 4);
      s += __shfl_xor(s, 8);
      if (bm == 0)
        ezG[l * N_B + n0 + (wave << 4) + (kg << 2) + r] = EXP2(ap * s);
    }
  } else {
    int t = (bid - 768) * 256 + tid;  // 0..4095
    size_t off = (size_t)t * 8;
    ushort8v H, L;
    split8(decW + off, 1.0f, H, L, nullptr);
    *(ushort8v*)(dwh + off) = H;
    *(ushort8v*)(dwl + off) = L;
  }
}

// ---------------------------------------------------------------------------
// K2: bid<1024: lse (XCD-swizzled, one l per XCD) + coherent partial store +
//              arrival atomicAdd;
//     bid<1152: zdec;
//     bid==1152: finalize — single spinner waits for 1024 arrivals, then
//              reduces partials (coherent loads, 8 in flight) -> scalar.
// ---------------------------------------------------------------------------
__global__ __launch_bounds__(256, 4) void k2_lse_zdec_finalize(
    const unsigned short* __restrict__ zhG, const unsigned short* __restrict__ zlG,
    const unsigned short* __restrict__ esh, const unsigned short* __restrict__ esl,
    const float* __restrict__ ezG,
    const unsigned short* __restrict__ dwh, const unsigned short* __restrict__ dwl,
    const float* __restrict__ decb,
    const float* __restrict__ en2G, const float* __restrict__ lsg,
    float* __restrict__ partials, float* __restrict__ zdec,
    float* __restrict__ out_scalar, unsigned* __restrict__ counters) {
  __shared__ __align__(16) unsigned char smem_raw[16384];
  const unsigned bid = blockIdx.x;
  const int tid = threadIdx.x;
  const int lane = tid & 63;
  const int wave = tid >> 6;
  const int bm = lane & 15;
  const int kg = lane >> 4;
  const int k0 = kg << 3;

  if (bid < 1024) {
    float(*red)[64] = (float(*)[64])smem_raw;
    const int wgid = (bid & 7) * 128 + (bid >> 3);  // XCD swizzle
    const int l = wgid >> 7;
    const int mt = (wgid >> 2) & 31;
    const int nb = wgid & 3;
    const int m0 = mt << 6;

    bf16x8 Bh0[4], Bh1[4], Bl0[4], Bl1[4];
    #pragma unroll
    for (int ms = 0; ms < 4; ++ms) {
      size_t base = ((size_t)(l * N_B) + m0 + ms * 16 + bm) * 64 + k0;
      Bh0[ms] = *(const bf16x8*)(esh + base);
      Bh1[ms] = *(const bf16x8*)(esh + base + 32);
      Bl0[ms] = *(const bf16x8*)(esl + base);
      Bl1[ms] = *(const bf16x8*)(esl + base + 32);
    }

    float sums[4] = {0.f, 0.f, 0.f, 0.f};
    const int nstart = (nb << 9) + (wave << 4);
    const unsigned short* zhP =
        zhG + ((size_t)(l * N_B) + nstart + bm) * 64 + k0;
    const unsigned short* zlP =
        zlG + ((size_t)(l * N_B) + nstart + bm) * 64 + k0;
    const float* ezP = ezG + l * N_B + nstart + (kg << 2);

    #pragma unroll 1
    for (int c = 0; c < 8; ++c) {
      bf16x8 ah0 = *(const bf16x8*)(zhP);
      bf16x8 ah1 = *(const bf16x8*)(zhP + 32);
      bf16x8 al0 = *(const bf16x8*)(zlP);
      bf16x8 al1 = *(const bf16x8*)(zlP + 32);
      f32x4 ezv = *(const f32x4*)(ezP);
      zhP += 64 * 64;  zlP += 64 * 64;  ezP += 64;
      #pragma unroll
      for (int ms = 0; ms < 4; ++ms) {
        f32x4 acc = {0.f, 0.f, 0.f, 0.f};
        acc = __builtin_amdgcn_mfma_f32_16x16x32_bf16(ah0, Bh0[ms], acc, 0, 0, 0);
        acc = __builtin_amdgcn_mfma_f32_16x16x32_bf16(ah1, Bh1[ms], acc, 0, 0, 0);
        acc = __builtin_amdgcn_mfma_f32_16x16x32_bf16(al0, Bh0[ms], acc, 0, 0, 0);
        acc = __builtin_amdgcn_mfma_f32_16x16x32_bf16(al1, Bh1[ms], acc, 0, 0, 0);
        acc = __builtin_amdgcn_mfma_f32_16x16x32_bf16(ah0, Bl0[ms], acc, 0, 0, 0);
        acc = __builtin_amdgcn_mfma_f32_16x16x32_bf16(ah1, Bl1[ms], acc, 0, 0, 0);
        sums[ms] = fmaf(ezv[0], EXP2(acc[0]), sums[ms]);
        sums[ms] = fmaf(ezv[1], EXP2(acc[1]), sums[ms]);
        sums[ms] = fmaf(ezv[2], EXP2(acc[2]), sums[ms]);
        sums[ms] = fmaf(ezv[3], EXP2(acc[3]), sums[ms]);
      }
    }

    #pragma unroll
    for (int ms = 0; ms < 4; ++ms) {
      float s = sums[ms];
      s += __shfl_xor(s, 16);
      s += __shfl_xor(s, 32);
      if (lane < 16) red[wave][ms * 16 + lane] = s;
    }
    __syncthreads();
    if (tid < 64) {
      float S = red[0][tid] + red[1][tid] + red[2][tid] + red[3][tid];
      store_f32_sys(&partials[(((size_t)(l * N_B)) + m0 + tid) * 4 + nb], S);
      VM_WAIT0;  // own coherent store drained before arrival
    }
    __syncthreads();
    if (tid == 0) atomicAdd(counters, 1u);  // device-scope arrival
  } else if (bid < 1152) {
    // ---- zdec ----
    f32x4(*redq)[4][64] = (f32x4(*)[4][64])smem_raw;
    const int n0 = (bid - 1024) << 4;
    f32x4 acc[4] = {{0.f, 0.f, 0.f, 0.f}, {0.f, 0.f, 0.f, 0.f},
                    {0.f, 0.f, 0.f, 0.f}, {0.f, 0.f, 0.f, 0.f}};
    #pragma unroll
    for (int jj = 0; jj < 4; ++jj) {
      int j = (wave << 2) + jj;
      int l = j >> 1;
      int off = ((j & 1) << 5) + k0;
      size_t ab = ((size_t)(l * N_B + n0 + bm)) * 64 + off;
      bf16x8 ah = *(const bf16x8*)(zhG + ab);
      bf16x8 al = *(const bf16x8*)(zlG + ab);
      #pragma unroll
      for (int ms = 0; ms < 4; ++ms) {
        int d = (ms << 4) + bm;
        size_t bb = (size_t)d * 512 + (j << 5) + k0;
        bf16x8 bh = *(const bf16x8*)(dwh + bb);
        bf16x8 bl = *(const bf16x8*)(dwl + bb);
        acc[ms] = __builtin_amdgcn_mfma_f32_16x16x32_bf16(ah, bh, acc[ms], 0, 0, 0);
        acc[ms] = __builtin_amdgcn_mfma_f32_16x16x32_bf16(al, bh, acc[ms], 0, 0, 0);
        acc[ms] = __builtin_amdgcn_mfma_f32_16x16x32_bf16(ah, bl, acc[ms], 0, 0, 0);
      }
    }
    #pragma unroll
    for (int ms = 0; ms < 4; ++ms) redq[wave][ms][lane] = acc[ms];
    __syncthreads();
    if (wave == 0) {
      #pragma unroll
      for (int ms = 0; ms < 4; ++ms) {
        f32x4 s = redq[0][ms][lane];
        #pragma unroll
        for (int w = 1; w < 4; ++w) {
          f32x4 t = redq[w][ms][lane];
          s[0] += t[0]; s[1] += t[1]; s[2] += t[2]; s[3] += t[3];
        }
        float bd = decb[(ms << 4) + bm];
        #pragma unroll
        for (int r = 0; r < 4; ++r)
          zdec[(size_t)(n0 + (kg << 2) + r) * 64 + (ms << 4) + bm] = s[r] + bd;
      }
    }
  } else {
    // ---- finalize: single spinner ----
    float* buf = (float*)smem_raw;
    if (tid == 0) {
      while (load_u32_sys(counters) < 1024u) __builtin_amdgcn_s_sleep(16);
    }
    __syncthreads();
    const float ls = lsg[0];
    const float sig = __expf(ls);
    const float ap = (-1.0f / (2.0f * sig * sig)) * 1.4426950408889634f;
    float local = 0.f;
    for (int i = 0; i < 64; i += 8) {
      f32x4 t[8];
      #pragma unroll
      for (int j = 0; j < 8; ++j)
        t[j] = load_f32x4_sys_nowait(partials +
                                     (size_t)(tid + ((i + j) << 8)) * 4);
      VM_WAIT0;
      #pragma unroll
      for (int j = 0; j < 8; ++j) {
        int idx = tid + ((i + j) << 8);
        float S = t[j][0] + t[j][1] + t[j][2] + t[j][3];
        local += ap * en2G[idx] + __log2f(S);
      }
    }
    #pragma unroll
    for (int off = 32; off; off >>= 1) local += __shfl_down(local, off);
    if (lane == 0) buf[wave] = local;
    __syncthreads();
    if (tid == 0) {
      float t = buf[0] + buf[1] + buf[2] + buf[3];
      float total = 0.69314718055994531f * t;
      float val = -total / (float)(L_L * N_B)
                + 0.5f * (float)D_D * (2.0f * ls - 1.0f)
                + logf((float)N_B);
      *out_scalar = val;
    }
  }
}

extern "C" void kernel_launch(void* const* d_in, const int* in_sizes, int n_in,
                              void* d_out, int out_size, void* d_ws, size_t ws_size,
                              hipStream_t stream) {
  const float* z    = (const float*)d_in[0];
  const float* e    = (const float*)d_in[1];
  const float* encW = (const float*)d_in[2];
  const float* encb = (const float*)d_in[3];
  const float* decW = (const float*)d_in[4];
  const float* decb = (const float*)d_in[5];
  const float* lsg  = (const float*)d_in[6];

  float* out    = (float*)d_out;
  float* zdec   = out;                                // [2048*64]
  float* zmulti = out + N_B * D_D;                    // [8*2048*64]
  float* lse    = out + N_B * D_D + L_L * N_B * D_D;  // [1]

  unsigned* counters = (unsigned*)d_ws;               // [16] (zeroed per call)
  float* partials = (float*)d_ws + 16;                // [65536]
  float* ez       = partials + 65536;                 // [16384]
  float* en2      = ez + 16384;                       // [16384]
  unsigned short* us = (unsigned short*)(en2 + 16384);
  unsigned short* esh = us;                 // [1048576]
  unsigned short* esl = esh + 1048576;
  unsigned short* zh  = esl + 1048576;      // [1048576]
  unsigned short* zl  = zh + 1048576;
  unsigned short* dwh = zl + 1048576;       // [32768]
  unsigned short* dwl = dwh + 32768;

  hipMemsetAsync(counters, 0, 64, stream);  // zero arrival counter each call
  k1_prep_encode<<<784, 256, 0, stream>>>(z, e, encW, encb, decW, lsg,
                                          zmulti, esh, esl, en2,
                                          zh, zl, ez, dwh, dwl);
  k2_lse_zdec_finalize<<<1153, 256, 0, stream>>>(zh, zl, esh, esl, ez,
                                                 dwh, dwl, decb, en2, lsg,
                                                 partials, zdec, lse, counters);
}

// Round 12
// 44.920 us; speedup vs baseline: 1.3206x; 1.3206x over previous
//
#include <hip/hip_runtime.h>
#include <math.h>

// Problem constants: N=2048, L=8, D=64, M=N=2048.
#define N_B 2048
#define L_L 8
#define D_D 64

typedef short bf16x8 __attribute__((ext_vector_type(8)));
typedef float f32x4 __attribute__((ext_vector_type(4)));
typedef unsigned short ushort8v __attribute__((ext_vector_type(8)));

#if __has_builtin(__builtin_amdgcn_exp2f)
#define EXP2(x) __builtin_amdgcn_exp2f(x)
#else
#define EXP2(x) exp2f(x)
#endif

// Split fp32 x into bf16 hi + bf16 lo (RTNE each). hi in high16, lo in low16.
__device__ __forceinline__ unsigned split_bf16_pack(float x) {
  unsigned u = __float_as_uint(x);
  unsigned rb = u + 0x7FFFu + ((u >> 16) & 1u);
  unsigned hbits = rb & 0xFFFF0000u;
  float res = x - __uint_as_float(hbits);
  unsigned u2 = __float_as_uint(res);
  unsigned rb2 = u2 + 0x7FFFu + ((u2 >> 16) & 1u);
  return hbits | (rb2 >> 16);
}

// Split 8 contiguous floats (scaled) into hi/lo ushort8 vectors.
__device__ __forceinline__ void split8(const float* __restrict__ src,
                                       float scale, ushort8v& H, ushort8v& L,
                                       float* ssq) {
  float4 v0 = *(const float4*)(src);
  float4 v1 = *(const float4*)(src + 4);
  float vv[8] = {v0.x, v0.y, v0.z, v0.w, v1.x, v1.y, v1.z, v1.w};
  #pragma unroll
  for (int t = 0; t < 8; ++t) {
    if (ssq) *ssq += vv[t] * vv[t];
    unsigned p = split_bf16_pack(scale * vv[t]);
    H[t] = (unsigned short)(p >> 16);
    L[t] = (unsigned short)(p & 0xFFFF);
  }
}

// Load 16 floats (k0..k0+7, k0+32..k0+39) from a 64-float row, split to frags.
// Works for LDS rows too (generic pointer -> ds_read after inlining).
__device__ __forceinline__ void load_split_row(const float* base, int k0,
                                               bf16x8& H0, bf16x8& L0,
                                               bf16x8& H1, bf16x8& L1) {
  float4 a0 = *(const float4*)(base + k0);
  float4 a1 = *(const float4*)(base + k0 + 4);
  float4 b0 = *(const float4*)(base + k0 + 32);
  float4 b1 = *(const float4*)(base + k0 + 36);
  float vv[16] = {a0.x, a0.y, a0.z, a0.w, a1.x, a1.y, a1.z, a1.w,
                  b0.x, b0.y, b0.z, b0.w, b1.x, b1.y, b1.z, b1.w};
  #pragma unroll
  for (int t = 0; t < 8; ++t) {
    unsigned p0 = split_bf16_pack(vv[t]);
    H0[t] = (short)(p0 >> 16); L0[t] = (short)(p0 & 0xFFFF);
    unsigned p1 = split_bf16_pack(vv[8 + t]);
    H1[t] = (short)(p1 >> 16); L1[t] = (short)(p1 & 0xFFFF);
  }
}

// ---------------------------------------------------------------------------
// K1: independent prep work in one launch.
//  bid [0,512):   e-split, XCD-aligned (l = bid&7 -> written on consumer XCD)
//  bid [512,768): encode: LDS-stage z-tile + encW-tile (coalesced), split from
//                 LDS, 6 split-MFMAs -> zm, zh/zl, ez = exp2(ap*||h||^2)
//  bid [768,784): decW split -> dwh/dwl
// ---------------------------------------------------------------------------
__global__ __launch_bounds__(256) void k1_prep_encode(
    const float* __restrict__ z, const float* __restrict__ e,
    const float* __restrict__ encW, const float* __restrict__ encb,
    const float* __restrict__ decW, const float* __restrict__ lsg,
    float* __restrict__ zm,
    unsigned short* __restrict__ esh, unsigned short* __restrict__ esl,
    float* __restrict__ en2G,
    unsigned short* __restrict__ zhG, unsigned short* __restrict__ zlG,
    float* __restrict__ ezG,
    unsigned short* __restrict__ dwh, unsigned short* __restrict__ dwl) {
  __shared__ __align__(16) float zT[64][68];
  __shared__ __align__(16) float wT[64][68];
  const unsigned bid = blockIdx.x;
  const int tid = threadIdx.x;
  const int lane = tid & 63;
  const int wave = tid >> 6;
  const int bm = lane & 15;
  const int kg = lane >> 4;
  const int k0 = kg << 3;

  const float ls = lsg[0];
  const float sig = __expf(ls);
  const float ap = (-1.0f / (2.0f * sig * sig)) * 1.4426950408889634f;
  const float se = -2.0f * ap;

  if (bid < 512) {
    const int l = bid & 7;
    const int sub = bid >> 3;                  // 0..63
    const int row = l * N_B + (sub << 5) + (tid >> 3);
    const int c = (tid & 7) << 3;
    size_t off = (size_t)row * 64 + c;
    ushort8v H, L;
    float ssq = 0.f;
    split8(e + off, se, H, L, &ssq);
    *(ushort8v*)(esh + off) = H;
    *(ushort8v*)(esl + off) = L;
    ssq += __shfl_xor(ssq, 1);
    ssq += __shfl_xor(ssq, 2);
    ssq += __shfl_xor(ssq, 4);
    if ((tid & 7) == 0) en2G[row] = ssq;
  } else if (bid < 768) {
    const int eb = bid - 512;
    const int l = eb & 7;
    const int nt = eb >> 3;
    const int n0 = nt << 6;
    {
      int r = tid >> 2, q = (tid & 3) << 4;
      const float4* zsrc = (const float4*)(z + (size_t)(n0 + r) * 64 + q);
      const float4* wsrc = (const float4*)(encW + (size_t)(l * 64 + r) * 64 + q);
      #pragma unroll
      for (int j = 0; j < 4; ++j) {
        *(float4*)&zT[r][q + j * 4] = zsrc[j];
        *(float4*)&wT[r][q + j * 4] = wsrc[j];
      }
    }
    __syncthreads();
    bf16x8 Bh0[4], Bh1[4], Bl0[4], Bl1[4];
    #pragma unroll
    for (int ms = 0; ms < 4; ++ms)
      load_split_row(&wT[ms * 16 + bm][0], k0,
                     Bh0[ms], Bl0[ms], Bh1[ms], Bl1[ms]);
    bf16x8 ah0, al0, ah1, al1;
    load_split_row(&zT[(wave << 4) + bm][0], k0, ah0, al0, ah1, al1);

    float sq[4] = {0.f, 0.f, 0.f, 0.f};
    #pragma unroll
    for (int ms = 0; ms < 4; ++ms) {
      float bi = encb[l * 64 + ms * 16 + bm];
      f32x4 acc = {bi, bi, bi, bi};
      acc = __builtin_amdgcn_mfma_f32_16x16x32_bf16(ah0, Bh0[ms], acc, 0, 0, 0);
      acc = __builtin_amdgcn_mfma_f32_16x16x32_bf16(ah1, Bh1[ms], acc, 0, 0, 0);
      acc = __builtin_amdgcn_mfma_f32_16x16x32_bf16(al0, Bh0[ms], acc, 0, 0, 0);
      acc = __builtin_amdgcn_mfma_f32_16x16x32_bf16(al1, Bh1[ms], acc, 0, 0, 0);
      acc = __builtin_amdgcn_mfma_f32_16x16x32_bf16(ah0, Bl0[ms], acc, 0, 0, 0);
      acc = __builtin_amdgcn_mfma_f32_16x16x32_bf16(ah1, Bl1[ms], acc, 0, 0, 0);
      #pragma unroll
      for (int r = 0; r < 4; ++r) {
        float v = acc[r];
        int nr = n0 + (wave << 4) + (kg << 2) + r;
        size_t idx = ((size_t)(l * N_B + nr)) * 64 + (ms << 4) + bm;
        zm[idx] = v;
        unsigned p = split_bf16_pack(v);
        zhG[idx] = (unsigned short)(p >> 16);
        zlG[idx] = (unsigned short)(p & 0xFFFF);
        sq[r] += v * v;
      }
    }
    #pragma unroll
    for (int r = 0; r < 4; ++r) {
      float s = sq[r];
      s += __shfl_xor(s, 1);
      s += __shfl_xor(s, 2);
      s += __shfl_xor(s, 4);
      s += __shfl_xor(s, 8);
      if (bm == 0)
        ezG[l * N_B + n0 + (wave << 4) + (kg << 2) + r] = EXP2(ap * s);
    }
  } else {
    int t = (bid - 768) * 256 + tid;  // 0..4095
    size_t off = (size_t)t * 8;
    ushort8v H, L;
    split8(decW + off, 1.0f, H, L, nullptr);
    *(ushort8v*)(dwh + off) = H;
    *(ushort8v*)(dwl + off) = L;
  }
}

// ---------------------------------------------------------------------------
// K2 (lse): grid 1024 = l(8) x mt(32) x nb(4), XCD-swizzled (one l per XCD).
// partial[l][m][nb] = sum_n ez_n * exp2( (-2ap) z_n.e_m )
// Depth-2 software pipeline: c+1's A/ez loads issue before c's MFMA block.
// ---------------------------------------------------------------------------
__global__ __launch_bounds__(256, 4) void lse_kernel(
    const unsigned short* __restrict__ zhG, const unsigned short* __restrict__ zlG,
    const unsigned short* __restrict__ esh, const unsigned short* __restrict__ esl,
    const float* __restrict__ ezG, float* __restrict__ partials) {
  __shared__ float red[4][64];
  const int wgid = (blockIdx.x & 7) * 128 + (blockIdx.x >> 3);
  const int l = wgid >> 7;
  const int mt = (wgid >> 2) & 31;
  const int nb = wgid & 3;
  const int m0 = mt << 6;
  const int tid = threadIdx.x;
  const int lane = tid & 63;
  const int wave = tid >> 6;
  const int bm = lane & 15;
  const int kg = lane >> 4;
  const int k0 = kg << 3;

  bf16x8 Bh0[4], Bh1[4], Bl0[4], Bl1[4];
  #pragma unroll
  for (int ms = 0; ms < 4; ++ms) {
    size_t base = ((size_t)(l * N_B) + m0 + ms * 16 + bm) * 64 + k0;
    Bh0[ms] = *(const bf16x8*)(esh + base);
    Bh1[ms] = *(const bf16x8*)(esh + base + 32);
    Bl0[ms] = *(const bf16x8*)(esl + base);
    Bl1[ms] = *(const bf16x8*)(esl + base + 32);
  }

  float sums[4] = {0.f, 0.f, 0.f, 0.f};
  const int nstart = (nb << 9) + (wave << 4);
  const unsigned short* zhP = zhG + ((size_t)(l * N_B) + nstart + bm) * 64 + k0;
  const unsigned short* zlP = zlG + ((size_t)(l * N_B) + nstart + bm) * 64 + k0;
  const float* ezP = ezG + l * N_B + nstart + (kg << 2);

  bf16x8 ah0 = *(const bf16x8*)(zhP);
  bf16x8 ah1 = *(const bf16x8*)(zhP + 32);
  bf16x8 al0 = *(const bf16x8*)(zlP);
  bf16x8 al1 = *(const bf16x8*)(zlP + 32);
  f32x4 ezv = *(const f32x4*)(ezP);

  auto compute = [&](bf16x8 ch0, bf16x8 ch1, bf16x8 cl0, bf16x8 cl1,
                     f32x4 cez) {
    #pragma unroll
    for (int ms = 0; ms < 4; ++ms) {
      f32x4 acc = {0.f, 0.f, 0.f, 0.f};
      acc = __builtin_amdgcn_mfma_f32_16x16x32_bf16(ch0, Bh0[ms], acc, 0, 0, 0);
      acc = __builtin_amdgcn_mfma_f32_16x16x32_bf16(ch1, Bh1[ms], acc, 0, 0, 0);
      acc = __builtin_amdgcn_mfma_f32_16x16x32_bf16(cl0, Bh0[ms], acc, 0, 0, 0);
      acc = __builtin_amdgcn_mfma_f32_16x16x32_bf16(cl1, Bh1[ms], acc, 0, 0, 0);
      acc = __builtin_amdgcn_mfma_f32_16x16x32_bf16(ch0, Bl0[ms], acc, 0, 0, 0);
      acc = __builtin_amdgcn_mfma_f32_16x16x32_bf16(ch1, Bl1[ms], acc, 0, 0, 0);
      sums[ms] = fmaf(cez[0], EXP2(acc[0]), sums[ms]);
      sums[ms] = fmaf(cez[1], EXP2(acc[1]), sums[ms]);
      sums[ms] = fmaf(cez[2], EXP2(acc[2]), sums[ms]);
      sums[ms] = fmaf(cez[3], EXP2(acc[3]), sums[ms]);
    }
  };

  #pragma unroll 1
  for (int c = 0; c < 7; ++c) {
    // prefetch c+1 (issues before the MFMA cluster; hides load latency)
    zhP += 64 * 64;  zlP += 64 * 64;  ezP += 64;
    bf16x8 nh0 = *(const bf16x8*)(zhP);
    bf16x8 nh1 = *(const bf16x8*)(zhP + 32);
    bf16x8 nl0 = *(const bf16x8*)(zlP);
    bf16x8 nl1 = *(const bf16x8*)(zlP + 32);
    f32x4 nez = *(const f32x4*)(ezP);
    compute(ah0, ah1, al0, al1, ezv);
    ah0 = nh0; ah1 = nh1; al0 = nl0; al1 = nl1; ezv = nez;
  }
  compute(ah0, ah1, al0, al1, ezv);

  #pragma unroll
  for (int ms = 0; ms < 4; ++ms) {
    float s = sums[ms];
    s += __shfl_xor(s, 16);
    s += __shfl_xor(s, 32);
    if (lane < 16) red[wave][ms * 16 + lane] = s;
  }
  __syncthreads();
  if (tid < 64) {
    float S = red[0][tid] + red[1][tid] + red[2][tid] + red[3][tid];
    partials[(((size_t)(l * N_B)) + m0 + tid) * 4 + nb] = S;
  }
}

// ---------------------------------------------------------------------------
// K3: zdec (bid<128) || whole finalize (bid==128), no intra-kernel deps.
// ---------------------------------------------------------------------------
__global__ __launch_bounds__(256) void k3_zdec_finalize(
    const unsigned short* __restrict__ zhG, const unsigned short* __restrict__ zlG,
    const unsigned short* __restrict__ dwh, const unsigned short* __restrict__ dwl,
    const float* __restrict__ decb,
    const float* __restrict__ partials, const float* __restrict__ en2G,
    const float* __restrict__ lsg,
    float* __restrict__ zdec, float* __restrict__ out_scalar) {
  __shared__ __align__(16) unsigned char smem_raw[16384];
  const unsigned bid = blockIdx.x;
  const int tid = threadIdx.x;
  const int lane = tid & 63;
  const int wave = tid >> 6;
  const int bm = lane & 15;
  const int kg = lane >> 4;
  const int k0 = kg << 3;

  if (bid < 128) {
    f32x4(*redq)[4][64] = (f32x4(*)[4][64])smem_raw;
    const int n0 = bid << 4;
    f32x4 acc[4] = {{0.f, 0.f, 0.f, 0.f}, {0.f, 0.f, 0.f, 0.f},
                    {0.f, 0.f, 0.f, 0.f}, {0.f, 0.f, 0.f, 0.f}};
    #pragma unroll
    for (int jj = 0; jj < 4; ++jj) {
      int j = (wave << 2) + jj;
      int l = j >> 1;
      int off = ((j & 1) << 5) + k0;
      size_t ab = ((size_t)(l * N_B + n0 + bm)) * 64 + off;
      bf16x8 ah = *(const bf16x8*)(zhG + ab);
      bf16x8 al = *(const bf16x8*)(zlG + ab);
      #pragma unroll
      for (int ms = 0; ms < 4; ++ms) {
        int d = (ms << 4) + bm;
        size_t bb = (size_t)d * 512 + (j << 5) + k0;
        bf16x8 bh = *(const bf16x8*)(dwh + bb);
        bf16x8 bl = *(const bf16x8*)(dwl + bb);
        acc[ms] = __builtin_amdgcn_mfma_f32_16x16x32_bf16(ah, bh, acc[ms], 0, 0, 0);
        acc[ms] = __builtin_amdgcn_mfma_f32_16x16x32_bf16(al, bh, acc[ms], 0, 0, 0);
        acc[ms] = __builtin_amdgcn_mfma_f32_16x16x32_bf16(ah, bl, acc[ms], 0, 0, 0);
      }
    }
    #pragma unroll
    for (int ms = 0; ms < 4; ++ms) redq[wave][ms][lane] = acc[ms];
    __syncthreads();
    if (wave == 0) {
      #pragma unroll
      for (int ms = 0; ms < 4; ++ms) {
        f32x4 s = redq[0][ms][lane];
        #pragma unroll
        for (int w = 1; w < 4; ++w) {
          f32x4 t = redq[w][ms][lane];
          s[0] += t[0]; s[1] += t[1]; s[2] += t[2]; s[3] += t[3];
        }
        float bd = decb[(ms << 4) + bm];
        #pragma unroll
        for (int r = 0; r < 4; ++r)
          zdec[(size_t)(n0 + (kg << 2) + r) * 64 + (ms << 4) + bm] = s[r] + bd;
      }
    }
  } else {
    // finalize: 256 threads cover all 16384 (l,m) rows, 64 each.
    float* buf = (float*)smem_raw;
    const float ls = lsg[0];
    const float sig = __expf(ls);
    const float ap = (-1.0f / (2.0f * sig * sig)) * 1.4426950408889634f;
    float local = 0.f;
    #pragma unroll 4
    for (int i = 0; i < 64; ++i) {
      int idx = tid + (i << 8);
      f32x4 p = *(const f32x4*)(partials + (size_t)idx * 4);
      float S = p[0] + p[1] + p[2] + p[3];
      local += ap * en2G[idx] + __log2f(S);
    }
    #pragma unroll
    for (int off = 32; off; off >>= 1) local += __shfl_down(local, off);
    if (lane == 0) buf[wave] = local;
    __syncthreads();
    if (tid == 0) {
      float t = buf[0] + buf[1] + buf[2] + buf[3];
      float total = 0.69314718055994531f * t;
      float val = -total / (float)(L_L * N_B)
                + 0.5f * (float)D_D * (2.0f * ls - 1.0f)
                + logf((float)N_B);
      *out_scalar = val;
    }
  }
}

extern "C" void kernel_launch(void* const* d_in, const int* in_sizes, int n_in,
                              void* d_out, int out_size, void* d_ws, size_t ws_size,
                              hipStream_t stream) {
  const float* z    = (const float*)d_in[0];
  const float* e    = (const float*)d_in[1];
  const float* encW = (const float*)d_in[2];
  const float* encb = (const float*)d_in[3];
  const float* decW = (const float*)d_in[4];
  const float* decb = (const float*)d_in[5];
  const float* lsg  = (const float*)d_in[6];

  float* out    = (float*)d_out;
  float* zdec   = out;                                // [2048*64]
  float* zmulti = out + N_B * D_D;                    // [8*2048*64]
  float* lse    = out + N_B * D_D + L_L * N_B * D_D;  // [1]

  float* partials = (float*)d_ws;                     // [65536]
  float* ez       = partials + 65536;                 // [16384]
  float* en2      = ez + 16384;                       // [16384]
  unsigned short* us = (unsigned short*)(en2 + 16384);
  unsigned short* esh = us;                 // [1048576]
  unsigned short* esl = esh + 1048576;
  unsigned short* zh  = esl + 1048576;      // [1048576]
  unsigned short* zl  = zh + 1048576;
  unsigned short* dwh = zl + 1048576;       // [32768]
  unsigned short* dwl = dwh + 32768;

  k1_prep_encode<<<784, 256, 0, stream>>>(z, e, encW, encb, decW, lsg,
                                          zmulti, esh, esl, en2,
                                          zh, zl, ez, dwh, dwl);
  lse_kernel<<<1024, 256, 0, stream>>>(zh, zl, esh, esl, ez, partials);
  k3_zdec_finalize<<<129, 256, 0, stream>>>(zh, zl, dwh, dwl, decb,
                                            partials, en2, lsg,
                                            zdec, lse);
}